// Round 1
// baseline (187.491 us; speedup 1.0000x reference)
//
#include <hip/hip_runtime.h>

// LogSumExpPooling2D: x (8,256,256,64) f32 NHWC ->
// out (1,128,128,64): (1/100)*logsumexp(100*x) over 2x2 stride-2 window AND batch.
// Memory-bound: 128 MiB read + 4 MiB write, ~21 us HBM floor.

constexpr float SCALE = 100.0f;
constexpr float INV_SCALE = 0.01f;

__global__ __launch_bounds__(256) void lse_pool_kernel(const float* __restrict__ x,
                                                       float* __restrict__ out) {
    // thread -> (ho, wo, channel-group of 4). 16 groups cover C=64.
    const int t   = blockIdx.x * 256 + threadIdx.x;   // 0 .. 128*128*16-1
    const int cg  = t & 15;
    const int pix = t >> 4;        // 0 .. 128*128-1
    const int wo  = pix & 127;
    const int ho  = pix >> 7;
    const int c   = cg << 2;
    const int h0  = ho << 1;
    const int w0  = wo << 1;

    // Load all 32 window values (8 n * 2 dh * 2 dw) as float4 (4 channels).
    float4 vals[32];
    int i = 0;
#pragma unroll
    for (int n = 0; n < 8; ++n) {
#pragma unroll
        for (int dh = 0; dh < 2; ++dh) {
#pragma unroll
            for (int dw = 0; dw < 2; ++dw) {
                const size_t off =
                    ((((size_t)n * 256 + (size_t)(h0 + dh)) * 256) + (size_t)(w0 + dw)) * 64
                    + (size_t)c;
                vals[i++] = *reinterpret_cast<const float4*>(x + off);
            }
        }
    }

    // Pass 1: max per channel (of raw x; scale folds out of the max).
    float4 m = vals[0];
#pragma unroll
    for (int k = 1; k < 32; ++k) {
        m.x = fmaxf(m.x, vals[k].x);
        m.y = fmaxf(m.y, vals[k].y);
        m.z = fmaxf(m.z, vals[k].z);
        m.w = fmaxf(m.w, vals[k].w);
    }

    // Pass 2: sum of exp(100*(v - m)). All args <= 0, no overflow.
    float4 s = make_float4(0.f, 0.f, 0.f, 0.f);
#pragma unroll
    for (int k = 0; k < 32; ++k) {
        s.x += __expf((vals[k].x - m.x) * SCALE);
        s.y += __expf((vals[k].y - m.y) * SCALE);
        s.z += __expf((vals[k].z - m.z) * SCALE);
        s.w += __expf((vals[k].w - m.w) * SCALE);
    }

    float4 r;
    r.x = m.x + __logf(s.x) * INV_SCALE;
    r.y = m.y + __logf(s.y) * INV_SCALE;
    r.z = m.z + __logf(s.z) * INV_SCALE;
    r.w = m.w + __logf(s.w) * INV_SCALE;

    // out flat index: (ho*128 + wo)*64 + c  == pix*64 + c
    *reinterpret_cast<float4*>(out + (size_t)pix * 64 + (size_t)c) = r;
}

extern "C" void kernel_launch(void* const* d_in, const int* in_sizes, int n_in,
                              void* d_out, int out_size, void* d_ws, size_t ws_size,
                              hipStream_t stream) {
    const float* x = (const float*)d_in[0];
    float* out = (float*)d_out;
    // 128*128 output pixels * 16 channel-groups = 262144 threads / 256 = 1024 blocks
    lse_pool_kernel<<<1024, 256, 0, stream>>>(x, out);
}

// Round 2
// 185.006 us; speedup vs baseline: 1.0134x; 1.0134x over previous
//
#include <hip/hip_runtime.h>

// LogSumExpPooling2D: x (8,256,256,64) f32 NHWC ->
// out (1,128,128,64): (1/100)*logsumexp(100*x) over 2x2 stride-2 window AND batch.
// Memory-bound: 128 MiB read + 4 MiB write, ~21 us HBM floor @ 6.3-6.9 TB/s.
//
// R2: online-chunked logsumexp (chunk = 2 batch images = 8 float4 live) to cut
// VGPR from ~200 (R1 held all 32 float4 -> spill/occupancy cliff) to ~60.

constexpr float SCALE = 100.0f;
constexpr float INV_SCALE = 0.01f;

__global__ __launch_bounds__(256, 6) void lse_pool_kernel(const float* __restrict__ x,
                                                          float* __restrict__ out) {
    // thread -> (ho, wo, channel-group of 4). 16 groups cover C=64.
    const int t   = blockIdx.x * 256 + threadIdx.x;   // 0 .. 128*128*16-1
    const int cg  = t & 15;
    const int pix = t >> 4;        // 0 .. 128*128-1
    const int wo  = pix & 127;
    const int ho  = pix >> 7;
    const int c   = cg << 2;
    const int h0  = ho << 1;
    const int w0  = wo << 1;

    const size_t NSTRIDE = (size_t)256 * 256 * 64;     // one batch image, floats
    const float* p = x + ((size_t)h0 * 256 + (size_t)w0) * 64 + (size_t)c;

    float m[4], s[4];
#pragma unroll
    for (int j = 0; j < 4; ++j) { m[j] = -1e30f; s[j] = 0.0f; }

#pragma unroll
    for (int np = 0; np < 4; ++np) {                   // chunk = batches 2np, 2np+1
        float4 v[8];
#pragma unroll
        for (int k = 0; k < 8; ++k) {                  // k = (n&1)<<2 | dh<<1 | dw
            const int n  = (np << 1) | (k >> 2);
            const int dh = (k >> 1) & 1;
            const int dw = k & 1;
            v[k] = *reinterpret_cast<const float4*>(
                p + (size_t)n * NSTRIDE + (size_t)(dh * 256 + dw) * 64);
        }

        // chunk max per channel
        float cm[4] = { v[0].x, v[0].y, v[0].z, v[0].w };
#pragma unroll
        for (int k = 1; k < 8; ++k) {
            cm[0] = fmaxf(cm[0], v[k].x);
            cm[1] = fmaxf(cm[1], v[k].y);
            cm[2] = fmaxf(cm[2], v[k].z);
            cm[3] = fmaxf(cm[3], v[k].w);
        }

        // chunk sum of exp(100*(v - cm)); args <= 0, no overflow
        float cs[4] = { 0.f, 0.f, 0.f, 0.f };
#pragma unroll
        for (int k = 0; k < 8; ++k) {
            cs[0] += __expf((v[k].x - cm[0]) * SCALE);
            cs[1] += __expf((v[k].y - cm[1]) * SCALE);
            cs[2] += __expf((v[k].z - cm[2]) * SCALE);
            cs[3] += __expf((v[k].w - cm[3]) * SCALE);
        }

        // merge running (m, s) with chunk (cm, cs)
#pragma unroll
        for (int j = 0; j < 4; ++j) {
            const float mn = fmaxf(m[j], cm[j]);
            s[j] = s[j] * __expf((m[j] - mn) * SCALE)
                 + cs[j] * __expf((cm[j] - mn) * SCALE);
            m[j] = mn;
        }
    }

    float4 r;
    r.x = m[0] + __logf(s[0]) * INV_SCALE;
    r.y = m[1] + __logf(s[1]) * INV_SCALE;
    r.z = m[2] + __logf(s[2]) * INV_SCALE;
    r.w = m[3] + __logf(s[3]) * INV_SCALE;

    *reinterpret_cast<float4*>(out + (size_t)pix * 64 + (size_t)c) = r;
}

extern "C" void kernel_launch(void* const* d_in, const int* in_sizes, int n_in,
                              void* d_out, int out_size, void* d_ws, size_t ws_size,
                              hipStream_t stream) {
    const float* x = (const float*)d_in[0];
    float* out = (float*)d_out;
    // 128*128 pixels * 16 channel-groups = 262144 threads / 256 = 1024 blocks
    lse_pool_kernel<<<1024, 256, 0, stream>>>(x, out);
}